// Round 2
// baseline (9391.252 us; speedup 1.0000x reference)
//
#include <hip/hip_runtime.h>
#include <stdint.h>

#define B_TOT 32768
#define A_N   32
#define D_N   64
#define H_N   128
#define KD    128   // 2*D
#define BT    16
#define NT    256

// ---------------- KT: transpose + widen weights into workspace --------------
// W1t[a][i][h] = (double)W1[a][h][i]
// W2t[a][h][d] = (double)W2[a][d][h]
// Wct[i][h]    = (double)Wr1[h][i]        (i < 128)
// Wpt[d][h]    = (double)Wr1[h][128 + d]  (d < 64)
__global__ __launch_bounds__(NT)
void kT(const float* __restrict__ W1, const float* __restrict__ W2,
        const float* __restrict__ Wr1,
        double* __restrict__ W1t, double* __restrict__ W2t,
        double* __restrict__ Wct, double* __restrict__ Wpt)
{
  const int a = blockIdx.x, part = blockIdx.y, tid = threadIdx.x;
  if (part < 8) {
    for (int e = part*2048 + tid; e < (part+1)*2048; e += NT) {
      int i = e >> 7, h = e & 127;
      W1t[((size_t)a*KD + i)*H_N + h] = (double)W1[((size_t)a*H_N + h)*KD + i];
    }
  } else if (part == 8) {
    for (int e = tid; e < H_N*D_N; e += NT) {
      int h = e >> 6, d = e & 63;
      W2t[((size_t)a*H_N + h)*D_N + d] = (double)W2[((size_t)a*D_N + d)*H_N + h];
    }
  } else {
    for (int e = a*768 + tid; e < (a+1)*768; e += NT) {
      if (e < 16384) {
        int i = e >> 7, h = e & 127;
        Wct[(size_t)i*H_N + h] = (double)Wr1[(size_t)h*192 + i];
      } else {
        int e2 = e - 16384; int d = e2 >> 7, h = e2 & 127;
        Wpt[(size_t)d*H_N + h] = (double)Wr1[(size_t)h*192 + 128 + d];
      }
    }
  }
}

// ---------------- K2: rewards[b,a]  (f64, ILP + LDS/VMEM restructured) ------
// Bit-exact vs previous round: every per-output fma chain keeps the same
// operand order (i-asc, h-asc, d-asc, same associations).
template<bool TR>
__global__ __launch_bounds__(NT, 4)
void k2_rewards(const int* __restrict__ x, const float* __restrict__ cemb,
                const float* __restrict__ W1, const float* __restrict__ b1,
                const float* __restrict__ W2, const float* __restrict__ b2,
                const float* __restrict__ Wr1, const float* __restrict__ br1,
                const float* __restrict__ Wr2,
                const double* __restrict__ W1t, const double* __restrict__ W2t,
                const double* __restrict__ Wct, const double* __restrict__ Wpt,
                double* __restrict__ rew)
{
  __shared__ double ctxd [BT][KD];    // ctx (phases 0-1); hctx after phase 1
  __shared__ double hidd [BT][KD];    // hidden; 'part' overlay in phase 3
  __shared__ double predd[BT][D_N];
  const int tid = threadIdx.x, b0 = blockIdx.x * BT, a = blockIdx.y;

  // ---- gather ctx (f64, exact from f32 source)
  for (int e = tid; e < BT*KD; e += NT) {
    int r = e >> 7, i = e & 127;
    int xi = x[(b0 + r)*2 + (i >> 6)];
    ctxd[r][i] = (double)cemb[(size_t)xi*D_N + (i & 63)];
  }
  __syncthreads();

  // ---- phase 1: R=2 rows x C=4 cols per thread -> 16 indep f64 chains
  const int cg = tid & 31, h0 = cg*4;
  const int r0 = (tid >> 5) * 2;
  double hid[2][4], hc[2][4];
  {
    #pragma unroll
    for (int c = 0; c < 4; ++c) {
      const double bi = (double)b1[a*H_N + h0 + c];
      hid[0][c] = bi; hid[1][c] = bi; hc[0][c] = 0.0; hc[1][c] = 0.0;
    }
    const double* pw1 = TR ? (W1t + (size_t)a*KD*H_N) : nullptr;
    for (int i = 0; i < KD; i += 4) {
      const double2 c0a = *(const double2*)&ctxd[r0  ][i];
      const double2 c0b = *(const double2*)&ctxd[r0  ][i+2];
      const double2 c1a = *(const double2*)&ctxd[r0+1][i];
      const double2 c1b = *(const double2*)&ctxd[r0+1][i+2];
      const double cA[4] = {c0a.x, c0a.y, c0b.x, c0b.y};
      const double cB[4] = {c1a.x, c1a.y, c1b.x, c1b.y};
      if constexpr (TR) {
        #pragma unroll
        for (int ii = 0; ii < 4; ++ii) {
          const double2 wa = *(const double2*)(pw1 + (size_t)(i+ii)*H_N + h0);
          const double2 wb = *(const double2*)(pw1 + (size_t)(i+ii)*H_N + h0 + 2);
          const double2 va = *(const double2*)(Wct + (size_t)(i+ii)*H_N + h0);
          const double2 vb = *(const double2*)(Wct + (size_t)(i+ii)*H_N + h0 + 2);
          const double aa = cA[ii], bb = cB[ii];
          hid[0][0] = fma(aa, wa.x, hid[0][0]); hid[1][0] = fma(bb, wa.x, hid[1][0]);
          hid[0][1] = fma(aa, wa.y, hid[0][1]); hid[1][1] = fma(bb, wa.y, hid[1][1]);
          hid[0][2] = fma(aa, wb.x, hid[0][2]); hid[1][2] = fma(bb, wb.x, hid[1][2]);
          hid[0][3] = fma(aa, wb.y, hid[0][3]); hid[1][3] = fma(bb, wb.y, hid[1][3]);
          hc[0][0]  = fma(aa, va.x, hc[0][0]);  hc[1][0]  = fma(bb, va.x, hc[1][0]);
          hc[0][1]  = fma(aa, va.y, hc[0][1]);  hc[1][1]  = fma(bb, va.y, hc[1][1]);
          hc[0][2]  = fma(aa, vb.x, hc[0][2]);  hc[1][2]  = fma(bb, vb.x, hc[1][2]);
          hc[0][3]  = fma(aa, vb.y, hc[0][3]);  hc[1][3]  = fma(bb, vb.y, hc[1][3]);
        }
      } else {
        #pragma unroll
        for (int c = 0; c < 4; ++c) {
          const float4 wf = *(const float4*)(W1 + ((size_t)a*H_N + h0 + c)*KD + i);
          const float4 vf = *(const float4*)(Wr1 + (size_t)(h0 + c)*192 + i);
          const double w0 = wf.x, w1_ = wf.y, w2_ = wf.z, w3_ = wf.w;
          const double v0 = vf.x, v1_ = vf.y, v2_ = vf.z, v3_ = vf.w;
          hid[0][c] = fma(cA[0], w0, hid[0][c]); hid[0][c] = fma(cA[1], w1_, hid[0][c]);
          hid[0][c] = fma(cA[2], w2_, hid[0][c]); hid[0][c] = fma(cA[3], w3_, hid[0][c]);
          hid[1][c] = fma(cB[0], w0, hid[1][c]); hid[1][c] = fma(cB[1], w1_, hid[1][c]);
          hid[1][c] = fma(cB[2], w2_, hid[1][c]); hid[1][c] = fma(cB[3], w3_, hid[1][c]);
          hc[0][c]  = fma(cA[0], v0, hc[0][c]);  hc[0][c]  = fma(cA[1], v1_, hc[0][c]);
          hc[0][c]  = fma(cA[2], v2_, hc[0][c]);  hc[0][c]  = fma(cA[3], v3_, hc[0][c]);
          hc[1][c]  = fma(cB[0], v0, hc[1][c]);  hc[1][c]  = fma(cB[1], v1_, hc[1][c]);
          hc[1][c]  = fma(cB[2], v2_, hc[1][c]);  hc[1][c]  = fma(cB[3], v3_, hc[1][c]);
        }
      }
    }
  }
  __syncthreads();            // all ctx reads done before ctxd reuse as hctx
  #pragma unroll
  for (int r = 0; r < 2; ++r) {
    #pragma unroll
    for (int c = 0; c < 4; ++c) {
      hidd[r0+r][h0+c] = hid[r][c];
      ctxd[r0+r][h0+c] = hc[r][c];   // ctxd now holds hctx
    }
  }
  __syncthreads();

  // ---- phase 2: R=1 row x C=4 d-cols per thread (h ascending, as before)
  {
    const int dg = tid & 15, d0 = dg*4, r2 = tid >> 4;
    double acc2[4];
    #pragma unroll
    for (int c = 0; c < 4; ++c) acc2[c] = (double)b2[a*D_N + d0 + c];
    const double* pw2 = TR ? (W2t + (size_t)a*H_N*D_N) : nullptr;
    for (int hh = 0; hh < H_N; hh += 4) {
      const double2 ha = *(const double2*)&hidd[r2][hh];
      const double2 hb = *(const double2*)&hidd[r2][hh+2];
      const double hv[4] = {ha.x, ha.y, hb.x, hb.y};
      if constexpr (TR) {
        #pragma unroll
        for (int jj = 0; jj < 4; ++jj) {
          const double2 wa = *(const double2*)(pw2 + (size_t)(hh+jj)*D_N + d0);
          const double2 wb = *(const double2*)(pw2 + (size_t)(hh+jj)*D_N + d0 + 2);
          acc2[0] = fma(hv[jj], wa.x, acc2[0]);
          acc2[1] = fma(hv[jj], wa.y, acc2[1]);
          acc2[2] = fma(hv[jj], wb.x, acc2[2]);
          acc2[3] = fma(hv[jj], wb.y, acc2[3]);
        }
      } else {
        #pragma unroll
        for (int c = 0; c < 4; ++c) {
          const float4 wf = *(const float4*)(W2 + ((size_t)a*D_N + d0 + c)*H_N + hh);
          acc2[c] = fma(hv[0], (double)wf.x, acc2[c]);
          acc2[c] = fma(hv[1], (double)wf.y, acc2[c]);
          acc2[c] = fma(hv[2], (double)wf.z, acc2[c]);
          acc2[c] = fma(hv[3], (double)wf.w, acc2[c]);
        }
      }
    }
    #pragma unroll
    for (int c = 0; c < 4; ++c) predd[r2][d0 + c] = acc2[c];
  }
  __syncthreads();

  // ---- phase 3: (r,g) layout, 8 interleaved pp chains (d ascending)
  const int r3 = tid >> 4, g = tid & 15;
  double pp[8];
  #pragma unroll
  for (int q = 0; q < 8; ++q) pp[q] = 0.0;
  for (int dd = 0; dd < D_N; dd += 4) {
    const double2 pa = *(const double2*)&predd[r3][dd];
    const double2 pb = *(const double2*)&predd[r3][dd+2];
    const double p0 = pa.x, p1 = pa.y, p2 = pb.x, p3 = pb.y;
    if constexpr (TR) {
      #pragma unroll
      for (int q = 0; q < 8; ++q) {
        const int h = g + 16*q;
        pp[q] = fma(p0, Wpt[(size_t)(dd+0)*H_N + h], pp[q]);
        pp[q] = fma(p1, Wpt[(size_t)(dd+1)*H_N + h], pp[q]);
        pp[q] = fma(p2, Wpt[(size_t)(dd+2)*H_N + h], pp[q]);
        pp[q] = fma(p3, Wpt[(size_t)(dd+3)*H_N + h], pp[q]);
      }
    } else {
      #pragma unroll
      for (int q = 0; q < 8; ++q) {
        const float4 wf = *(const float4*)(Wr1 + (size_t)(g + 16*q)*192 + 128 + dd);
        pp[q] = fma(p0, (double)wf.x, pp[q]);
        pp[q] = fma(p1, (double)wf.y, pp[q]);
        pp[q] = fma(p2, (double)wf.z, pp[q]);
        pp[q] = fma(p3, (double)wf.w, pp[q]);
      }
    }
  }
  double sv = 0.0;
  #pragma unroll
  for (int q = 0; q < 8; ++q) {
    const int h = g + 16*q;
    const double t = ctxd[r3][h] + pp[q] + (double)br1[h];   // ctxd holds hctx
    const double gr = (t > 0.0) ? t : ((t == t) ? 0.0 : t);  // NaN-propagating relu
    sv = fma(gr, (double)Wr2[h], sv);
  }
  double* part = &hidd[0][0];          // hidd dead after phase 2 -> overlay
  part[r3*17 + g] = sv;
  __syncthreads();
  if (tid < BT) {
    double s2 = 0.0;
    for (int q = 0; q < 16; ++q) s2 += part[tid*17 + q];
    rew[(size_t)(b0 + tid)*A_N + a] = s2;
  }
}

// ---------------- K3: sel[b] = np-exact argmin over 32 rewards --------------
__global__ __launch_bounds__(NT)
void k3_argmin(const double* __restrict__ rew, int* __restrict__ sel)
{
  int b = blockIdx.x * NT + threadIdx.x;
  if (b >= B_TOT) return;
  const double* rr = rew + (size_t)b*A_N;
  double best = rr[0]; int idx = 0;
  for (int a = 1; a < A_N; ++a) {
    double v = rr[a];
    if (!(best != best) && ((v != v) || (v < best))) { best = v; idx = a; }
  }
  sel[b] = idx;
}

// ---------------- K4: out_r[b,:] = preds[b, sel[b], :]  (f32 out) -----------
template<bool TR>
__global__ __launch_bounds__(NT)
void k4_out(const int* __restrict__ x, const float* __restrict__ cemb,
            const float* __restrict__ W1, const float* __restrict__ b1,
            const float* __restrict__ W2, const float* __restrict__ b2,
            const double* __restrict__ W1t, const double* __restrict__ W2t,
            const int* __restrict__ sel, float* __restrict__ out_r)
{
  __shared__ double ctxd[BT][KD];
  __shared__ double hidd[BT][KD];
  __shared__ int sels[BT];
  const int tid = threadIdx.x, b0 = blockIdx.x * BT;
  for (int e = tid; e < BT*KD; e += NT) {
    int r = e >> 7, i = e & 127;
    int xi = x[(b0 + r)*2 + (i >> 6)];
    ctxd[r][i] = (double)cemb[(size_t)xi*D_N + (i & 63)];
  }
  if (tid < BT) sels[tid] = sel[b0 + tid];
  __syncthreads();

  // phase 1: R=1 row x C=8 cols per thread
  {
    const int cg = tid & 15, h0 = cg*8, r = tid >> 4;
    const int a = sels[r];
    double acc[8];
    #pragma unroll
    for (int c = 0; c < 8; ++c) acc[c] = (double)b1[a*H_N + h0 + c];
    const double* pw1 = TR ? (W1t + (size_t)a*KD*H_N) : nullptr;
    for (int i = 0; i < KD; i += 4) {
      const double2 ca = *(const double2*)&ctxd[r][i];
      const double2 cb = *(const double2*)&ctxd[r][i+2];
      const double cv[4] = {ca.x, ca.y, cb.x, cb.y};
      if constexpr (TR) {
        #pragma unroll
        for (int ii = 0; ii < 4; ++ii) {
          const double* wrow = pw1 + (size_t)(i+ii)*H_N + h0;
          #pragma unroll
          for (int c = 0; c < 8; ++c) acc[c] = fma(cv[ii], wrow[c], acc[c]);
        }
      } else {
        #pragma unroll
        for (int c = 0; c < 8; ++c) {
          const float4 wf = *(const float4*)(W1 + ((size_t)a*H_N + h0 + c)*KD + i);
          acc[c] = fma(cv[0], (double)wf.x, acc[c]);
          acc[c] = fma(cv[1], (double)wf.y, acc[c]);
          acc[c] = fma(cv[2], (double)wf.z, acc[c]);
          acc[c] = fma(cv[3], (double)wf.w, acc[c]);
        }
      }
    }
    #pragma unroll
    for (int c = 0; c < 8; ++c) hidd[r][h0 + c] = acc[c];
  }
  __syncthreads();

  // phase 2: R=1 row x C=4 d-cols per thread, f32 store
  {
    const int dg = tid & 15, d0 = dg*4, r2 = tid >> 4;
    const int a = sels[r2];
    double acc2[4];
    #pragma unroll
    for (int c = 0; c < 4; ++c) acc2[c] = (double)b2[a*D_N + d0 + c];
    const double* pw2 = TR ? (W2t + (size_t)a*H_N*D_N) : nullptr;
    for (int hh = 0; hh < H_N; hh += 4) {
      const double2 ha = *(const double2*)&hidd[r2][hh];
      const double2 hb = *(const double2*)&hidd[r2][hh+2];
      const double hv[4] = {ha.x, ha.y, hb.x, hb.y};
      if constexpr (TR) {
        #pragma unroll
        for (int jj = 0; jj < 4; ++jj) {
          const double2 wa = *(const double2*)(pw2 + (size_t)(hh+jj)*D_N + d0);
          const double2 wb = *(const double2*)(pw2 + (size_t)(hh+jj)*D_N + d0 + 2);
          acc2[0] = fma(hv[jj], wa.x, acc2[0]);
          acc2[1] = fma(hv[jj], wa.y, acc2[1]);
          acc2[2] = fma(hv[jj], wb.x, acc2[2]);
          acc2[3] = fma(hv[jj], wb.y, acc2[3]);
        }
      } else {
        #pragma unroll
        for (int c = 0; c < 4; ++c) {
          const float4 wf = *(const float4*)(W2 + ((size_t)a*D_N + d0 + c)*H_N + hh);
          acc2[c] = fma(hv[0], (double)wf.x, acc2[c]);
          acc2[c] = fma(hv[1], (double)wf.y, acc2[c]);
          acc2[c] = fma(hv[2], (double)wf.z, acc2[c]);
          acc2[c] = fma(hv[3], (double)wf.w, acc2[c]);
        }
      }
    }
    float4 o;
    o.x = (float)acc2[0]; o.y = (float)acc2[1];
    o.z = (float)acc2[2]; o.w = (float)acc2[3];
    *(float4*)(out_r + (size_t)(b0 + r2)*D_N + d0) = o;
  }
}

// ---------------- K5: wemb gather (f32 out) ---------------------------------
__global__ __launch_bounds__(NT)
void k5_wemb(const int* __restrict__ y, const float* __restrict__ wtab,
             float* __restrict__ out)
{
  int i = blockIdx.x * NT + threadIdx.x;   // over B*64
  int b = i >> 6, d = i & 63;
  out[i] = wtab[(size_t)y[b]*D_N + d];     // FLOAT32 output
}

extern "C" void kernel_launch(void* const* d_in, const int* in_sizes, int n_in,
                              void* d_out, int out_size, void* d_ws, size_t ws_size,
                              hipStream_t stream) {
  (void)in_sizes; (void)n_in; (void)out_size;
  const int*   x    = (const int*)d_in[0];
  const int*   y    = (const int*)d_in[1];
  const float* cemb = (const float*)d_in[2];
  const float* wemb = (const float*)d_in[3];
  const float* W1   = (const float*)d_in[4];
  const float* b1   = (const float*)d_in[5];
  const float* W2   = (const float*)d_in[6];
  const float* b2   = (const float*)d_in[7];
  const float* Wr1  = (const float*)d_in[8];
  const float* br1  = (const float*)d_in[9];
  const float* Wr2  = (const float*)d_in[10];
  // br2 (d_in[11]): constant shift of all rewards -> argmin-invariant; unused.

  // ws layout: rew f64[B][32] @0 (8 MiB); sel i32[B] @8MiB (128 KiB);
  //            W1t f64 @9MiB (16 MiB); W2t f64 @25MiB (4 MiB);
  //            Wct f64 @29MiB (128 KiB); Wpt f64 @29MiB+128KiB (64 KiB)
  double* ws_rew = (double*)d_ws;
  int*    ws_sel = (int*)((char*)d_ws + (8ull<<20));
  double* W1t    = (double*)((char*)d_ws + (9ull<<20));
  double* W2t    = (double*)((char*)d_ws + (25ull<<20));
  double* Wct    = (double*)((char*)d_ws + (29ull<<20));
  double* Wpt    = (double*)((char*)d_ws + (29ull<<20) + (128ull<<10));
  const bool tr = ws_size >= (30ull<<20);

  float* out_r    = (float*)d_out;                    // [B][64] f32
  float* out_wemb = out_r + (size_t)B_TOT * D_N;      // [B][64] f32

  if (tr) {
    kT<<<dim3(32, 10), dim3(NT), 0, stream>>>(W1, W2, Wr1, W1t, W2t, Wct, Wpt);
    k2_rewards<true><<<dim3(B_TOT/BT, A_N), dim3(NT), 0, stream>>>(
        x, cemb, W1, b1, W2, b2, Wr1, br1, Wr2, W1t, W2t, Wct, Wpt, ws_rew);
  } else {
    k2_rewards<false><<<dim3(B_TOT/BT, A_N), dim3(NT), 0, stream>>>(
        x, cemb, W1, b1, W2, b2, Wr1, br1, Wr2, nullptr, nullptr, nullptr, nullptr, ws_rew);
  }
  k3_argmin<<<dim3(B_TOT/NT), dim3(NT), 0, stream>>>(ws_rew, ws_sel);
  if (tr) {
    k4_out<true><<<dim3(B_TOT/BT), dim3(NT), 0, stream>>>(
        x, cemb, W1, b1, W2, b2, W1t, W2t, ws_sel, out_r);
  } else {
    k4_out<false><<<dim3(B_TOT/BT), dim3(NT), 0, stream>>>(
        x, cemb, W1, b1, W2, b2, nullptr, nullptr, ws_sel, out_r);
  }
  k5_wemb<<<dim3(B_TOT*D_N/NT), dim3(NT), 0, stream>>>(y, wemb, out_wemb);
}

// Round 3
// 3246.555 us; speedup vs baseline: 2.8927x; 2.8927x over previous
//
#include <hip/hip_runtime.h>
#include <stdint.h>

#define B_TOT 32768
#define A_N   32
#define D_N   64
#define H_N   128
#define KD    128   // 2*D
#define BT    16
#define NT    256

// ---------------- KT: transpose + widen weights into workspace --------------
// Paired layout: index [((row_k/2)*COLS + col)*2 + (row_k&1)] so one 16-B load
// yields the weight for k and k+1 at a given output column (lane-consecutive).
// W1t[a][i2][h][p] = W1[a][h][2*i2+p]
// W2t[a][h2][d][p] = W2[a][d][2*h2+p]
// Wct[i2][h][p]    = Wr1[h][2*i2+p]          (i < 128)
// Wpt[d2][h][p]    = Wr1[h][128 + 2*d2+p]    (d < 64)
__global__ __launch_bounds__(NT)
void kT(const float* __restrict__ W1, const float* __restrict__ W2,
        const float* __restrict__ Wr1,
        double* __restrict__ W1t, double* __restrict__ W2t,
        double* __restrict__ Wct, double* __restrict__ Wpt)
{
  const int a = blockIdx.x, part = blockIdx.y, tid = threadIdx.x;
  if (part < 8) {
    for (int e = part*2048 + tid; e < (part+1)*2048; e += NT) {
      int i = e >> 7, h = e & 127;
      W1t[(((size_t)a*64 + (i>>1))*H_N + h)*2 + (i&1)] =
          (double)W1[((size_t)a*H_N + h)*KD + i];
    }
  } else if (part == 8) {
    for (int e = tid; e < H_N*D_N; e += NT) {
      int h = e >> 6, d = e & 63;
      W2t[(((size_t)a*64 + (h>>1))*D_N + d)*2 + (h&1)] =
          (double)W2[((size_t)a*D_N + d)*H_N + h];
    }
  } else {
    for (int e = a*768 + tid; e < (a+1)*768; e += NT) {
      if (e < 16384) {
        int i = e >> 7, h = e & 127;
        Wct[((size_t)(i>>1)*H_N + h)*2 + (i&1)] = (double)Wr1[(size_t)h*192 + i];
      } else {
        int e2 = e - 16384; int d = e2 >> 7, h = e2 & 127;
        Wpt[((size_t)(d>>1)*H_N + h)*2 + (d&1)] =
            (double)Wr1[(size_t)h*192 + 128 + d];
      }
    }
  }
}

// ---------------- K2: rewards[b,a] ------------------------------------------
// All main-loop LDS reads are wave-uniform broadcasts; all LDS writes are
// lane-consecutive (both measured conflict-free in round 1). LDS = 40960 B
// exactly -> 4 blocks/CU. Per-output fma chains keep i/h/d ascending order
// with identical association -> rewards bit-identical to rounds 0-2.
template<bool TR>
__global__ __launch_bounds__(NT, 4)
void k2_rewards(const int* __restrict__ x, const float* __restrict__ cemb,
                const float* __restrict__ W1, const float* __restrict__ b1,
                const float* __restrict__ W2, const float* __restrict__ b2,
                const float* __restrict__ Wr1, const float* __restrict__ br1,
                const float* __restrict__ Wr2,
                const double* __restrict__ W1t, const double* __restrict__ W2t,
                const double* __restrict__ Wct, const double* __restrict__ Wpt,
                double* __restrict__ rew)
{
  __shared__ double ctxd [BT][KD];    // ctx; holds hctx after phase 1
  __shared__ double hidd [BT][KD];    // hidden; gr-buffer overlay in phase 3
  __shared__ double predd[BT][D_N];   // preds; part overlay in reduce
  const int tid = threadIdx.x, b0 = blockIdx.x * BT, a = blockIdx.y;

  // ---- gather ctx (f64, exact from f32 source)
  for (int e = tid; e < BT*KD; e += NT) {
    int r = e >> 7, i = e & 127;
    int xi = x[(b0 + r)*2 + (i >> 6)];
    ctxd[r][i] = (double)cemb[(size_t)xi*D_N + (i & 63)];
  }
  __syncthreads();

  const int h3 = tid & 127;           // owned h-column (phases 1,3)
  const int rb = (tid >> 7) * 8;      // 8-row group (wave-uniform)
  const int cg = tid & 63;            // owned d-column (phase 2)
  const int r0 = (tid >> 6) * 4;      // 4-row group (wave-uniform, phase 2)

  // ---- phase 1: hctx[r,h] = ctx . Wr1[h,:128]; hidden[r,h] = ctx.W1[a,h,:]+b1
  //      thread: column h3, rows rb..rb+7 -> 16 independent f64 chains.
  double hid[8], hc[8];
  {
    const double b1v = (double)b1[a*H_N + h3];
    #pragma unroll
    for (int q = 0; q < 8; ++q) { hid[q] = b1v; hc[q] = 0.0; }
    if constexpr (TR) {
      const double* pw1 = W1t + (size_t)a*(64*H_N*2);
      #pragma unroll 2
      for (int i2 = 0; i2 < 64; ++i2) {
        const double2 w = *(const double2*)(pw1 + ((size_t)i2*H_N + h3)*2);
        const double2 v = *(const double2*)(Wct + ((size_t)i2*H_N + h3)*2);
        #pragma unroll
        for (int q = 0; q < 8; ++q) {
          const double2 c = *(const double2*)&ctxd[rb+q][2*i2];  // broadcast
          hid[q] = fma(c.x, w.x, hid[q]); hid[q] = fma(c.y, w.y, hid[q]);
          hc[q]  = fma(c.x, v.x, hc[q]);  hc[q]  = fma(c.y, v.y, hc[q]);
        }
      }
    } else {
      const float* pw = W1 + ((size_t)a*H_N + h3)*KD;
      const float* pv = Wr1 + (size_t)h3*192;
      for (int i2 = 0; i2 < 64; ++i2) {
        const float2 wf = *(const float2*)(pw + 2*i2);
        const float2 vf = *(const float2*)(pv + 2*i2);
        const double wx = wf.x, wy = wf.y, vx = vf.x, vy = vf.y;
        #pragma unroll
        for (int q = 0; q < 8; ++q) {
          const double2 c = *(const double2*)&ctxd[rb+q][2*i2];
          hid[q] = fma(c.x, wx, hid[q]); hid[q] = fma(c.y, wy, hid[q]);
          hc[q]  = fma(c.x, vx, hc[q]);  hc[q]  = fma(c.y, vy, hc[q]);
        }
      }
    }
  }
  __syncthreads();   // all cross-wave ctx reads done before ctxd reuse as hctx
  #pragma unroll
  for (int q = 0; q < 8; ++q) {
    hidd[rb+q][h3] = hid[q];     // lane-consecutive writes
    ctxd[rb+q][h3] = hc[q];      // ctxd now holds hctx
  }
  __syncthreads();

  // ---- phase 2: preds[r,d] = hidden . W2[a,d,:] + b2  (h ascending)
  //      thread: column cg, rows r0..r0+3; hidd reads broadcast.
  {
    double a2[4];
    const double b2v = (double)b2[a*D_N + cg];
    #pragma unroll
    for (int q = 0; q < 4; ++q) a2[q] = b2v;
    if constexpr (TR) {
      const double* pw2 = W2t + (size_t)a*(64*D_N*2);
      #pragma unroll 2
      for (int h2 = 0; h2 < 64; ++h2) {
        const double2 w = *(const double2*)(pw2 + ((size_t)h2*D_N + cg)*2);
        #pragma unroll
        for (int q = 0; q < 4; ++q) {
          const double2 hv = *(const double2*)&hidd[r0+q][2*h2];  // broadcast
          a2[q] = fma(hv.x, w.x, a2[q]); a2[q] = fma(hv.y, w.y, a2[q]);
        }
      }
    } else {
      const float* pw = W2 + ((size_t)a*D_N + cg)*H_N;
      for (int h2 = 0; h2 < 64; ++h2) {
        const float2 wf = *(const float2*)(pw + 2*h2);
        const double wx = wf.x, wy = wf.y;
        #pragma unroll
        for (int q = 0; q < 4; ++q) {
          const double2 hv = *(const double2*)&hidd[r0+q][2*h2];
          a2[q] = fma(hv.x, wx, a2[q]); a2[q] = fma(hv.y, wy, a2[q]);
        }
      }
    }
    #pragma unroll
    for (int q = 0; q < 4; ++q) predd[r0+q][cg] = a2[q];   // lane-consecutive
  }
  __syncthreads();

  // ---- phase 3: thread: column h3, rows rb..rb+7; predd/hctx reads broadcast
  {
    double pp[8];
    #pragma unroll
    for (int q = 0; q < 8; ++q) pp[q] = 0.0;
    if constexpr (TR) {
      #pragma unroll 2
      for (int d2 = 0; d2 < 32; ++d2) {
        const double2 w = *(const double2*)(Wpt + ((size_t)d2*H_N + h3)*2);
        #pragma unroll
        for (int q = 0; q < 8; ++q) {
          const double2 p = *(const double2*)&predd[rb+q][2*d2];  // broadcast
          pp[q] = fma(p.x, w.x, pp[q]); pp[q] = fma(p.y, w.y, pp[q]);
        }
      }
    } else {
      const float* pw = Wr1 + (size_t)h3*192 + 128;
      for (int d2 = 0; d2 < 32; ++d2) {
        const float2 wf = *(const float2*)(pw + 2*d2);
        const double wx = wf.x, wy = wf.y;
        #pragma unroll
        for (int q = 0; q < 8; ++q) {
          const double2 p = *(const double2*)&predd[rb+q][2*d2];
          pp[q] = fma(p.x, wx, pp[q]); pp[q] = fma(p.y, wy, pp[q]);
        }
      }
    }
    const double brv = (double)br1[h3];
    double* grbuf = &hidd[0][0];       // hidd dead after phase 2 -> overlay
    #pragma unroll
    for (int q = 0; q < 8; ++q) {
      const double t = ctxd[rb+q][h3] + pp[q] + brv;          // ctxd holds hctx
      const double gr = (t > 0.0) ? t : ((t == t) ? 0.0 : t); // NaN-prop relu
      grbuf[(size_t)(rb+q)*KD + h3] = gr;                     // lane-consecutive
    }
  }
  __syncthreads();

  // ---- reduce, replaying the ORIGINAL fma chain exactly:
  //      part[r][g] = fma-chain over q of gr(h=g+16q)*Wr2;  s2 = sum_g part.
  {
    const int r = tid >> 4, g = tid & 15;
    const double* grbuf = &hidd[0][0];
    double pg = 0.0;
    #pragma unroll
    for (int q = 0; q < 8; ++q) {
      const int hq = g + 16*q;
      pg = fma(grbuf[(size_t)r*KD + hq], (double)Wr2[hq], pg);
    }
    predd[r][g] = pg;                  // part overlay (predd reads done)
  }
  __syncthreads();
  if (tid < BT) {
    double s2 = 0.0;
    for (int g = 0; g < 16; ++g) s2 += predd[tid][g];
    rew[(size_t)(b0 + tid)*A_N + a] = s2;
  }
}

// ---------------- K3: sel[b] = np-exact argmin over 32 rewards --------------
__global__ __launch_bounds__(NT)
void k3_argmin(const double* __restrict__ rew, int* __restrict__ sel)
{
  int b = blockIdx.x * NT + threadIdx.x;
  if (b >= B_TOT) return;
  const double* rr = rew + (size_t)b*A_N;
  double best = rr[0]; int idx = 0;
  for (int a = 1; a < A_N; ++a) {
    double v = rr[a];
    if (!(best != best) && ((v != v) || (v < best))) { best = v; idx = a; }
  }
  sel[b] = idx;
}

// ---------------- K4: out_r[b,:] = preds[b, sel[b], :]  (f32 out) -----------
template<bool TR>
__global__ __launch_bounds__(NT)
void k4_out(const int* __restrict__ x, const float* __restrict__ cemb,
            const float* __restrict__ W1, const float* __restrict__ b1,
            const float* __restrict__ W2, const float* __restrict__ b2,
            const double* __restrict__ W1t, const double* __restrict__ W2t,
            const int* __restrict__ sel, float* __restrict__ out_r)
{
  __shared__ double ctxd[BT][KD];
  __shared__ double hidd[BT][KD];
  __shared__ int sels[BT];
  const int tid = threadIdx.x, b0 = blockIdx.x * BT;
  for (int e = tid; e < BT*KD; e += NT) {
    int r = e >> 7, i = e & 127;
    int xi = x[(b0 + r)*2 + (i >> 6)];
    ctxd[r][i] = (double)cemb[(size_t)xi*D_N + (i & 63)];
  }
  if (tid < BT) sels[tid] = sel[b0 + tid];
  __syncthreads();

  // phase 1: R=1 row x C=8 cols per thread (i ascending)
  {
    const int r = tid >> 4, h0 = (tid & 15)*8;
    const int a = sels[r];
    double acc[8];
    #pragma unroll
    for (int c = 0; c < 8; ++c) acc[c] = (double)b1[a*H_N + h0 + c];
    if constexpr (TR) {
      const double* pw1 = W1t + (size_t)a*(64*H_N*2);
      for (int i2 = 0; i2 < 64; ++i2) {
        const double2 cv = *(const double2*)&ctxd[r][2*i2];
        #pragma unroll
        for (int c = 0; c < 8; ++c) {
          const double2 w = *(const double2*)(pw1 + ((size_t)i2*H_N + h0 + c)*2);
          acc[c] = fma(cv.x, w.x, acc[c]); acc[c] = fma(cv.y, w.y, acc[c]);
        }
      }
    } else {
      for (int i = 0; i < KD; i += 4) {
        const double2 ca = *(const double2*)&ctxd[r][i];
        const double2 cb = *(const double2*)&ctxd[r][i+2];
        const double cv[4] = {ca.x, ca.y, cb.x, cb.y};
        #pragma unroll
        for (int c = 0; c < 8; ++c) {
          const float4 wf = *(const float4*)(W1 + ((size_t)a*H_N + h0 + c)*KD + i);
          acc[c] = fma(cv[0], (double)wf.x, acc[c]);
          acc[c] = fma(cv[1], (double)wf.y, acc[c]);
          acc[c] = fma(cv[2], (double)wf.z, acc[c]);
          acc[c] = fma(cv[3], (double)wf.w, acc[c]);
        }
      }
    }
    #pragma unroll
    for (int c = 0; c < 8; ++c) hidd[r][h0 + c] = acc[c];
  }
  __syncthreads();

  // phase 2: R=1 row x C=4 d-cols per thread (h ascending), f32 store
  {
    const int dg = tid & 15, d0 = dg*4, r2 = tid >> 4;
    const int a = sels[r2];
    double acc2[4];
    #pragma unroll
    for (int c = 0; c < 4; ++c) acc2[c] = (double)b2[a*D_N + d0 + c];
    if constexpr (TR) {
      const double* pw2 = W2t + (size_t)a*(64*D_N*2);
      for (int h2 = 0; h2 < 64; ++h2) {
        const double2 hv = *(const double2*)&hidd[r2][2*h2];
        #pragma unroll
        for (int c = 0; c < 4; ++c) {
          const double2 w = *(const double2*)(pw2 + ((size_t)h2*D_N + d0 + c)*2);
          acc2[c] = fma(hv.x, w.x, acc2[c]); acc2[c] = fma(hv.y, w.y, acc2[c]);
        }
      }
    } else {
      for (int hh = 0; hh < H_N; hh += 4) {
        const double2 ha = *(const double2*)&hidd[r2][hh];
        const double2 hb = *(const double2*)&hidd[r2][hh+2];
        const double hv[4] = {ha.x, ha.y, hb.x, hb.y};
        #pragma unroll
        for (int c = 0; c < 4; ++c) {
          const float4 wf = *(const float4*)(W2 + ((size_t)a*D_N + d0 + c)*H_N + hh);
          acc2[c] = fma(hv[0], (double)wf.x, acc2[c]);
          acc2[c] = fma(hv[1], (double)wf.y, acc2[c]);
          acc2[c] = fma(hv[2], (double)wf.z, acc2[c]);
          acc2[c] = fma(hv[3], (double)wf.w, acc2[c]);
        }
      }
    }
    float4 o;
    o.x = (float)acc2[0]; o.y = (float)acc2[1];
    o.z = (float)acc2[2]; o.w = (float)acc2[3];
    *(float4*)(out_r + (size_t)(b0 + r2)*D_N + d0) = o;
  }
}

// ---------------- K5: wemb gather (f32 out) ---------------------------------
__global__ __launch_bounds__(NT)
void k5_wemb(const int* __restrict__ y, const float* __restrict__ wtab,
             float* __restrict__ out)
{
  int i = blockIdx.x * NT + threadIdx.x;   // over B*64
  int b = i >> 6, d = i & 63;
  out[i] = wtab[(size_t)y[b]*D_N + d];     // FLOAT32 output
}

extern "C" void kernel_launch(void* const* d_in, const int* in_sizes, int n_in,
                              void* d_out, int out_size, void* d_ws, size_t ws_size,
                              hipStream_t stream) {
  (void)in_sizes; (void)n_in; (void)out_size;
  const int*   x    = (const int*)d_in[0];
  const int*   y    = (const int*)d_in[1];
  const float* cemb = (const float*)d_in[2];
  const float* wemb = (const float*)d_in[3];
  const float* W1   = (const float*)d_in[4];
  const float* b1   = (const float*)d_in[5];
  const float* W2   = (const float*)d_in[6];
  const float* b2   = (const float*)d_in[7];
  const float* Wr1  = (const float*)d_in[8];
  const float* br1  = (const float*)d_in[9];
  const float* Wr2  = (const float*)d_in[10];
  // br2 (d_in[11]): constant shift of all rewards -> argmin-invariant; unused.

  // ws layout: rew f64[B][32] @0 (8 MiB); sel i32[B] @8MiB;
  //            W1t f64 @9MiB (4 MiB); W2t f64 @25MiB (2 MiB);
  //            Wct f64 @29MiB (128 KiB); Wpt f64 @29MiB+128KiB (64 KiB)
  double* ws_rew = (double*)d_ws;
  int*    ws_sel = (int*)((char*)d_ws + (8ull<<20));
  double* W1t    = (double*)((char*)d_ws + (9ull<<20));
  double* W2t    = (double*)((char*)d_ws + (25ull<<20));
  double* Wct    = (double*)((char*)d_ws + (29ull<<20));
  double* Wpt    = (double*)((char*)d_ws + (29ull<<20) + (128ull<<10));
  const bool tr = ws_size >= (30ull<<20);

  float* out_r    = (float*)d_out;                    // [B][64] f32
  float* out_wemb = out_r + (size_t)B_TOT * D_N;      // [B][64] f32

  if (tr) {
    kT<<<dim3(32, 10), dim3(NT), 0, stream>>>(W1, W2, Wr1, W1t, W2t, Wct, Wpt);
    k2_rewards<true><<<dim3(B_TOT/BT, A_N), dim3(NT), 0, stream>>>(
        x, cemb, W1, b1, W2, b2, Wr1, br1, Wr2, W1t, W2t, Wct, Wpt, ws_rew);
  } else {
    k2_rewards<false><<<dim3(B_TOT/BT, A_N), dim3(NT), 0, stream>>>(
        x, cemb, W1, b1, W2, b2, Wr1, br1, Wr2, nullptr, nullptr, nullptr, nullptr, ws_rew);
  }
  k3_argmin<<<dim3(B_TOT/NT), dim3(NT), 0, stream>>>(ws_rew, ws_sel);
  if (tr) {
    k4_out<true><<<dim3(B_TOT/BT), dim3(NT), 0, stream>>>(
        x, cemb, W1, b1, W2, b2, W1t, W2t, ws_sel, out_r);
  } else {
    k4_out<false><<<dim3(B_TOT/BT), dim3(NT), 0, stream>>>(
        x, cemb, W1, b1, W2, b2, nullptr, nullptr, ws_sel, out_r);
  }
  k5_wemb<<<dim3(B_TOT*D_N/NT), dim3(NT), 0, stream>>>(y, wemb, out_wemb);
}

// Round 4
// 3193.230 us; speedup vs baseline: 2.9410x; 1.0167x over previous
//
#include <hip/hip_runtime.h>
#include <stdint.h>

#define B_TOT 32768
#define A_N   32
#define D_N   64
#define H_N   128
#define KD    128   // 2*D
#define BT    16
#define NT    256

// ---------------- KT: transpose + widen weights into workspace --------------
// Paired layout: index [((row_k/2)*COLS + col)*2 + (row_k&1)] so one 16-B load
// yields the weight for k and k+1 at a given output column (lane-consecutive).
// W1t[a][i2][h][p] = W1[a][h][2*i2+p]
// W2t[a][h2][d][p] = W2[a][d][2*h2+p]
// Wct[i2][h][p]    = Wr1[h][2*i2+p]          (i < 128)
// Wpt[d2][h][p]    = Wr1[h][128 + 2*d2+p]    (d < 64)
__global__ __launch_bounds__(NT)
void kT(const float* __restrict__ W1, const float* __restrict__ W2,
        const float* __restrict__ Wr1,
        double* __restrict__ W1t, double* __restrict__ W2t,
        double* __restrict__ Wct, double* __restrict__ Wpt)
{
  const int a = blockIdx.x, part = blockIdx.y, tid = threadIdx.x;
  if (part < 8) {
    for (int e = part*2048 + tid; e < (part+1)*2048; e += NT) {
      int i = e >> 7, h = e & 127;
      W1t[(((size_t)a*64 + (i>>1))*H_N + h)*2 + (i&1)] =
          (double)W1[((size_t)a*H_N + h)*KD + i];
    }
  } else if (part == 8) {
    for (int e = tid; e < H_N*D_N; e += NT) {
      int h = e >> 6, d = e & 63;
      W2t[(((size_t)a*64 + (h>>1))*D_N + d)*2 + (h&1)] =
          (double)W2[((size_t)a*D_N + d)*H_N + h];
    }
  } else {
    for (int e = a*768 + tid; e < (a+1)*768; e += NT) {
      if (e < 16384) {
        int i = e >> 7, h = e & 127;
        Wct[((size_t)(i>>1)*H_N + h)*2 + (i&1)] = (double)Wr1[(size_t)h*192 + i];
      } else {
        int e2 = e - 16384; int d = e2 >> 7, h = e2 & 127;
        Wpt[((size_t)(d>>1)*H_N + h)*2 + (d&1)] =
            (double)Wr1[(size_t)h*192 + 128 + d];
      }
    }
  }
}

// ---------------- K1: hctx[b][h] = ctx . Wr1[h,:128]  (a-independent hoist) --
// Chain is byte-identical to the round-3 in-kernel hc chain: acc=0.0, i asc,
// fma(c.x,v.x) then fma(c.y,v.y) per i2.
__global__ __launch_bounds__(NT)
void k1_hctx(const int* __restrict__ x, const float* __restrict__ cemb,
             const double* __restrict__ Wct, double* __restrict__ hctxW)
{
  __shared__ double ctxd[BT][KD];
  const int tid = threadIdx.x, b0 = blockIdx.x * BT;
  for (int e = tid; e < BT*KD; e += NT) {
    int r = e >> 7, i = e & 127;
    int xi = x[(b0 + r)*2 + (i >> 6)];
    ctxd[r][i] = (double)cemb[(size_t)xi*D_N + (i & 63)];
  }
  __syncthreads();
  const int h0  = (tid & 63) * 2;       // 2 owned h-columns
  const int rb4 = (tid >> 6) * 4;       // 4 rows (wave-uniform)
  double hc[4][2];
  #pragma unroll
  for (int q = 0; q < 4; ++q) { hc[q][0] = 0.0; hc[q][1] = 0.0; }
  #pragma unroll 2
  for (int i2 = 0; i2 < 64; ++i2) {
    const double2 v0 = *(const double2*)(Wct + ((size_t)i2*H_N + h0    )*2);
    const double2 v1 = *(const double2*)(Wct + ((size_t)i2*H_N + h0 + 1)*2);
    #pragma unroll
    for (int q = 0; q < 4; ++q) {
      const double2 c = *(const double2*)&ctxd[rb4+q][2*i2];   // broadcast
      hc[q][0] = fma(c.x, v0.x, hc[q][0]); hc[q][0] = fma(c.y, v0.y, hc[q][0]);
      hc[q][1] = fma(c.x, v1.x, hc[q][1]); hc[q][1] = fma(c.y, v1.y, hc[q][1]);
    }
  }
  #pragma unroll
  for (int q = 0; q < 4; ++q) {
    double2 o; o.x = hc[q][0]; o.y = hc[q][1];
    *(double2*)&hctxW[(size_t)(b0 + rb4 + q)*H_N + h0] = o;    // coalesced
  }
}

// ---------------- K2: rewards[b,a] ------------------------------------------
// HX=true: hctx loaded from workspace; all phases retiled 2-cols x N-rows so
// each broadcast LDS read feeds 2x the FMAs. HX=false: exact round-3 kernel.
// Per-output fma chains keep i/h/d ascending order with identical association
// -> rewards bit-identical across all rounds.
template<bool TR, bool HX>
__global__ __launch_bounds__(NT, 4)
void k2_rewards(const int* __restrict__ x, const float* __restrict__ cemb,
                const float* __restrict__ W1, const float* __restrict__ b1,
                const float* __restrict__ W2, const float* __restrict__ b2,
                const float* __restrict__ Wr1, const float* __restrict__ br1,
                const float* __restrict__ Wr2,
                const double* __restrict__ W1t, const double* __restrict__ W2t,
                const double* __restrict__ Wct, const double* __restrict__ Wpt,
                const double* __restrict__ hctxW,
                double* __restrict__ rew)
{
  __shared__ double ctxd [BT][KD];    // ctx; holds hctx after phase 1
  __shared__ double hidd [BT][KD];    // hidden; gr-buffer overlay in phase 3
  __shared__ double predd[BT][D_N];   // preds; part overlay in reduce
  const int tid = threadIdx.x, b0 = blockIdx.x * BT, a = blockIdx.y;

  // ---- gather ctx (f64, exact from f32 source)
  for (int e = tid; e < BT*KD; e += NT) {
    int r = e >> 7, i = e & 127;
    int xi = x[(b0 + r)*2 + (i >> 6)];
    ctxd[r][i] = (double)cemb[(size_t)xi*D_N + (i & 63)];
  }
  __syncthreads();

  if constexpr (HX) {
    const int h0  = (tid & 63) * 2;     // 2 owned h-columns (phases 1,3)
    const int rb4 = (tid >> 6) * 4;     // 4 rows (wave-uniform)

    // ---- phase 1: hidden[r,h] = ctx . W1[a,h,:] + b1   (hctx hoisted to k1)
    {
      double hid[4][2];
      const double b1x = (double)b1[a*H_N + h0];
      const double b1y = (double)b1[a*H_N + h0 + 1];
      #pragma unroll
      for (int q = 0; q < 4; ++q) { hid[q][0] = b1x; hid[q][1] = b1y; }
      const double* pw1 = W1t + (size_t)a*(64*H_N*2);
      #pragma unroll 2
      for (int i2 = 0; i2 < 64; ++i2) {
        const double2 w0 = *(const double2*)(pw1 + ((size_t)i2*H_N + h0    )*2);
        const double2 w1 = *(const double2*)(pw1 + ((size_t)i2*H_N + h0 + 1)*2);
        #pragma unroll
        for (int q = 0; q < 4; ++q) {
          const double2 c = *(const double2*)&ctxd[rb4+q][2*i2];   // broadcast
          hid[q][0] = fma(c.x, w0.x, hid[q][0]); hid[q][0] = fma(c.y, w0.y, hid[q][0]);
          hid[q][1] = fma(c.x, w1.x, hid[q][1]); hid[q][1] = fma(c.y, w1.y, hid[q][1]);
        }
      }
      #pragma unroll
      for (int q = 0; q < 4; ++q) {
        double2 o; o.x = hid[q][0]; o.y = hid[q][1];
        *(double2*)&hidd[rb4+q][h0] = o;          // lane-consecutive
      }
    }
    __syncthreads();   // all ctx reads done before ctxd reuse as hctx
    // ---- overlay: load hctx (f64, bit-exact) into ctxd
    for (int e = tid; e < BT*64; e += NT) {
      int r = e >> 6, c2 = (e & 63)*2;
      *(double2*)&ctxd[r][c2] =
          *(const double2*)&hctxW[(size_t)(b0 + r)*H_N + c2];   // coalesced
    }
    __syncthreads();

    // ---- phase 2: preds[r,d] = hidden . W2[a,d,:] + b2  (2 cols x 2 rows)
    {
      const int d0 = (tid & 31) * 2;
      const int r2 = (tid >> 5) * 2;
      double a2[2][2];
      const double b2x = (double)b2[a*D_N + d0];
      const double b2y = (double)b2[a*D_N + d0 + 1];
      a2[0][0] = b2x; a2[0][1] = b2y; a2[1][0] = b2x; a2[1][1] = b2y;
      const double* pw2 = W2t + (size_t)a*(64*D_N*2);
      #pragma unroll 2
      for (int h2 = 0; h2 < 64; ++h2) {
        const double2 w0 = *(const double2*)(pw2 + ((size_t)h2*D_N + d0    )*2);
        const double2 w1 = *(const double2*)(pw2 + ((size_t)h2*D_N + d0 + 1)*2);
        #pragma unroll
        for (int q = 0; q < 2; ++q) {
          const double2 hv = *(const double2*)&hidd[r2+q][2*h2];  // 2-way bcast
          a2[q][0] = fma(hv.x, w0.x, a2[q][0]); a2[q][0] = fma(hv.y, w0.y, a2[q][0]);
          a2[q][1] = fma(hv.x, w1.x, a2[q][1]); a2[q][1] = fma(hv.y, w1.y, a2[q][1]);
        }
      }
      #pragma unroll
      for (int q = 0; q < 2; ++q) {
        double2 o; o.x = a2[q][0]; o.y = a2[q][1];
        *(double2*)&predd[r2+q][d0] = o;          // lane-consecutive
      }
    }
    __syncthreads();

    // ---- phase 3: pp + relu + gr  (2 cols x 4 rows; broadcast reads)
    {
      double pp[4][2];
      #pragma unroll
      for (int q = 0; q < 4; ++q) { pp[q][0] = 0.0; pp[q][1] = 0.0; }
      #pragma unroll 2
      for (int d2 = 0; d2 < 32; ++d2) {
        const double2 w0 = *(const double2*)(Wpt + ((size_t)d2*H_N + h0    )*2);
        const double2 w1 = *(const double2*)(Wpt + ((size_t)d2*H_N + h0 + 1)*2);
        #pragma unroll
        for (int q = 0; q < 4; ++q) {
          const double2 p = *(const double2*)&predd[rb4+q][2*d2];  // broadcast
          pp[q][0] = fma(p.x, w0.x, pp[q][0]); pp[q][0] = fma(p.y, w0.y, pp[q][0]);
          pp[q][1] = fma(p.x, w1.x, pp[q][1]); pp[q][1] = fma(p.y, w1.y, pp[q][1]);
        }
      }
      const double brx = (double)br1[h0], bry = (double)br1[h0 + 1];
      double* grbuf = &hidd[0][0];       // hidd dead after phase 2 -> overlay
      #pragma unroll
      for (int q = 0; q < 4; ++q) {
        const double2 hcv = *(const double2*)&ctxd[rb4+q][h0];    // hctx
        const double t0 = hcv.x + pp[q][0] + brx;
        const double t1 = hcv.y + pp[q][1] + bry;
        const double g0 = (t0 > 0.0) ? t0 : ((t0 == t0) ? 0.0 : t0);
        const double g1 = (t1 > 0.0) ? t1 : ((t1 == t1) ? 0.0 : t1);
        double2 o; o.x = g0; o.y = g1;
        *(double2*)&grbuf[(size_t)(rb4+q)*KD + h0] = o;           // lane-consec
      }
    }
    __syncthreads();
  } else {
    // ================== round-3 proven path (HX=false) ==================
    const int h3 = tid & 127;
    const int rb = (tid >> 7) * 8;
    const int cg = tid & 63;
    const int r0 = (tid >> 6) * 4;

    double hid[8], hc[8];
    {
      const double b1v = (double)b1[a*H_N + h3];
      #pragma unroll
      for (int q = 0; q < 8; ++q) { hid[q] = b1v; hc[q] = 0.0; }
      if constexpr (TR) {
        const double* pw1 = W1t + (size_t)a*(64*H_N*2);
        #pragma unroll 2
        for (int i2 = 0; i2 < 64; ++i2) {
          const double2 w = *(const double2*)(pw1 + ((size_t)i2*H_N + h3)*2);
          const double2 v = *(const double2*)(Wct + ((size_t)i2*H_N + h3)*2);
          #pragma unroll
          for (int q = 0; q < 8; ++q) {
            const double2 c = *(const double2*)&ctxd[rb+q][2*i2];
            hid[q] = fma(c.x, w.x, hid[q]); hid[q] = fma(c.y, w.y, hid[q]);
            hc[q]  = fma(c.x, v.x, hc[q]);  hc[q]  = fma(c.y, v.y, hc[q]);
          }
        }
      } else {
        const float* pw = W1 + ((size_t)a*H_N + h3)*KD;
        const float* pv = Wr1 + (size_t)h3*192;
        for (int i2 = 0; i2 < 64; ++i2) {
          const float2 wf = *(const float2*)(pw + 2*i2);
          const float2 vf = *(const float2*)(pv + 2*i2);
          const double wx = wf.x, wy = wf.y, vx = vf.x, vy = vf.y;
          #pragma unroll
          for (int q = 0; q < 8; ++q) {
            const double2 c = *(const double2*)&ctxd[rb+q][2*i2];
            hid[q] = fma(c.x, wx, hid[q]); hid[q] = fma(c.y, wy, hid[q]);
            hc[q]  = fma(c.x, vx, hc[q]);  hc[q]  = fma(c.y, vy, hc[q]);
          }
        }
      }
    }
    __syncthreads();
    #pragma unroll
    for (int q = 0; q < 8; ++q) {
      hidd[rb+q][h3] = hid[q];
      ctxd[rb+q][h3] = hc[q];
    }
    __syncthreads();

    {
      double a2[4];
      const double b2v = (double)b2[a*D_N + cg];
      #pragma unroll
      for (int q = 0; q < 4; ++q) a2[q] = b2v;
      if constexpr (TR) {
        const double* pw2 = W2t + (size_t)a*(64*D_N*2);
        #pragma unroll 2
        for (int h2 = 0; h2 < 64; ++h2) {
          const double2 w = *(const double2*)(pw2 + ((size_t)h2*D_N + cg)*2);
          #pragma unroll
          for (int q = 0; q < 4; ++q) {
            const double2 hv = *(const double2*)&hidd[r0+q][2*h2];
            a2[q] = fma(hv.x, w.x, a2[q]); a2[q] = fma(hv.y, w.y, a2[q]);
          }
        }
      } else {
        const float* pw = W2 + ((size_t)a*D_N + cg)*H_N;
        for (int h2 = 0; h2 < 64; ++h2) {
          const float2 wf = *(const float2*)(pw + 2*h2);
          const double wx = wf.x, wy = wf.y;
          #pragma unroll
          for (int q = 0; q < 4; ++q) {
            const double2 hv = *(const double2*)&hidd[r0+q][2*h2];
            a2[q] = fma(hv.x, wx, a2[q]); a2[q] = fma(hv.y, wy, a2[q]);
          }
        }
      }
      #pragma unroll
      for (int q = 0; q < 4; ++q) predd[r0+q][cg] = a2[q];
    }
    __syncthreads();

    {
      double pp[8];
      #pragma unroll
      for (int q = 0; q < 8; ++q) pp[q] = 0.0;
      if constexpr (TR) {
        #pragma unroll 2
        for (int d2 = 0; d2 < 32; ++d2) {
          const double2 w = *(const double2*)(Wpt + ((size_t)d2*H_N + h3)*2);
          #pragma unroll
          for (int q = 0; q < 8; ++q) {
            const double2 p = *(const double2*)&predd[rb+q][2*d2];
            pp[q] = fma(p.x, w.x, pp[q]); pp[q] = fma(p.y, w.y, pp[q]);
          }
        }
      } else {
        const float* pw = Wr1 + (size_t)h3*192 + 128;
        for (int d2 = 0; d2 < 32; ++d2) {
          const float2 wf = *(const float2*)(pw + 2*d2);
          const double wx = wf.x, wy = wf.y;
          #pragma unroll
          for (int q = 0; q < 8; ++q) {
            const double2 p = *(const double2*)&predd[rb+q][2*d2];
            pp[q] = fma(p.x, wx, pp[q]); pp[q] = fma(p.y, wy, pp[q]);
          }
        }
      }
      const double brv = (double)br1[h3];
      double* grbuf = &hidd[0][0];
      #pragma unroll
      for (int q = 0; q < 8; ++q) {
        const double t = ctxd[rb+q][h3] + pp[q] + brv;
        const double gr = (t > 0.0) ? t : ((t == t) ? 0.0 : t);
        grbuf[(size_t)(rb+q)*KD + h3] = gr;
      }
    }
    __syncthreads();
  }

  // ---- reduce, replaying the ORIGINAL fma chain exactly:
  //      part[r][g] = fma-chain over q of gr(h=g+16q)*Wr2;  s2 = sum_g part.
  {
    const int r = tid >> 4, g = tid & 15;
    const double* grbuf = &hidd[0][0];
    double pg = 0.0;
    #pragma unroll
    for (int q = 0; q < 8; ++q) {
      const int hq = g + 16*q;
      pg = fma(grbuf[(size_t)r*KD + hq], (double)Wr2[hq], pg);
    }
    predd[r][g] = pg;                  // part overlay (predd reads done)
  }
  __syncthreads();
  if (tid < BT) {
    double s2 = 0.0;
    for (int g = 0; g < 16; ++g) s2 += predd[tid][g];
    rew[(size_t)(b0 + tid)*A_N + a] = s2;
  }
}

// ---------------- K3: sel[b] = np-exact argmin over 32 rewards --------------
__global__ __launch_bounds__(NT)
void k3_argmin(const double* __restrict__ rew, int* __restrict__ sel)
{
  int b = blockIdx.x * NT + threadIdx.x;
  if (b >= B_TOT) return;
  const double* rr = rew + (size_t)b*A_N;
  double best = rr[0]; int idx = 0;
  for (int a = 1; a < A_N; ++a) {
    double v = rr[a];
    if (!(best != best) && ((v != v) || (v < best))) { best = v; idx = a; }
  }
  sel[b] = idx;
}

// ---------------- K4: out_r[b,:] = preds[b, sel[b], :]  (f32 out) -----------
template<bool TR>
__global__ __launch_bounds__(NT)
void k4_out(const int* __restrict__ x, const float* __restrict__ cemb,
            const float* __restrict__ W1, const float* __restrict__ b1,
            const float* __restrict__ W2, const float* __restrict__ b2,
            const double* __restrict__ W1t, const double* __restrict__ W2t,
            const int* __restrict__ sel, float* __restrict__ out_r)
{
  __shared__ double ctxd[BT][KD];
  __shared__ double hidd[BT][KD];
  __shared__ int sels[BT];
  const int tid = threadIdx.x, b0 = blockIdx.x * BT;
  for (int e = tid; e < BT*KD; e += NT) {
    int r = e >> 7, i = e & 127;
    int xi = x[(b0 + r)*2 + (i >> 6)];
    ctxd[r][i] = (double)cemb[(size_t)xi*D_N + (i & 63)];
  }
  if (tid < BT) sels[tid] = sel[b0 + tid];
  __syncthreads();

  // phase 1: R=1 row x C=8 cols per thread (i ascending)
  {
    const int r = tid >> 4, h0 = (tid & 15)*8;
    const int a = sels[r];
    double acc[8];
    #pragma unroll
    for (int c = 0; c < 8; ++c) acc[c] = (double)b1[a*H_N + h0 + c];
    if constexpr (TR) {
      const double* pw1 = W1t + (size_t)a*(64*H_N*2);
      for (int i2 = 0; i2 < 64; ++i2) {
        const double2 cv = *(const double2*)&ctxd[r][2*i2];
        #pragma unroll
        for (int c = 0; c < 8; ++c) {
          const double2 w = *(const double2*)(pw1 + ((size_t)i2*H_N + h0 + c)*2);
          acc[c] = fma(cv.x, w.x, acc[c]); acc[c] = fma(cv.y, w.y, acc[c]);
        }
      }
    } else {
      for (int i = 0; i < KD; i += 4) {
        const double2 ca = *(const double2*)&ctxd[r][i];
        const double2 cb = *(const double2*)&ctxd[r][i+2];
        const double cv[4] = {ca.x, ca.y, cb.x, cb.y};
        #pragma unroll
        for (int c = 0; c < 8; ++c) {
          const float4 wf = *(const float4*)(W1 + ((size_t)a*H_N + h0 + c)*KD + i);
          acc[c] = fma(cv[0], (double)wf.x, acc[c]);
          acc[c] = fma(cv[1], (double)wf.y, acc[c]);
          acc[c] = fma(cv[2], (double)wf.z, acc[c]);
          acc[c] = fma(cv[3], (double)wf.w, acc[c]);
        }
      }
    }
    #pragma unroll
    for (int c = 0; c < 8; ++c) hidd[r][h0 + c] = acc[c];
  }
  __syncthreads();

  // phase 2: R=1 row x C=4 d-cols per thread (h ascending), f32 store
  {
    const int dg = tid & 15, d0 = dg*4, r2 = tid >> 4;
    const int a = sels[r2];
    double acc2[4];
    #pragma unroll
    for (int c = 0; c < 4; ++c) acc2[c] = (double)b2[a*D_N + d0 + c];
    if constexpr (TR) {
      const double* pw2 = W2t + (size_t)a*(64*D_N*2);
      for (int h2 = 0; h2 < 64; ++h2) {
        const double2 hv = *(const double2*)&hidd[r2][2*h2];
        #pragma unroll
        for (int c = 0; c < 4; ++c) {
          const double2 w = *(const double2*)(pw2 + ((size_t)h2*D_N + d0 + c)*2);
          acc2[c] = fma(hv.x, w.x, acc2[c]); acc2[c] = fma(hv.y, w.y, acc2[c]);
        }
      }
    } else {
      for (int hh = 0; hh < H_N; hh += 4) {
        const double2 ha = *(const double2*)&hidd[r2][hh];
        const double2 hb = *(const double2*)&hidd[r2][hh+2];
        const double hv[4] = {ha.x, ha.y, hb.x, hb.y};
        #pragma unroll
        for (int c = 0; c < 4; ++c) {
          const float4 wf = *(const float4*)(W2 + ((size_t)a*D_N + d0 + c)*H_N + hh);
          acc2[c] = fma(hv[0], (double)wf.x, acc2[c]);
          acc2[c] = fma(hv[1], (double)wf.y, acc2[c]);
          acc2[c] = fma(hv[2], (double)wf.z, acc2[c]);
          acc2[c] = fma(hv[3], (double)wf.w, acc2[c]);
        }
      }
    }
    float4 o;
    o.x = (float)acc2[0]; o.y = (float)acc2[1];
    o.z = (float)acc2[2]; o.w = (float)acc2[3];
    *(float4*)(out_r + (size_t)(b0 + r2)*D_N + d0) = o;
  }
}

// ---------------- K5: wemb gather (f32 out) ---------------------------------
__global__ __launch_bounds__(NT)
void k5_wemb(const int* __restrict__ y, const float* __restrict__ wtab,
             float* __restrict__ out)
{
  int i = blockIdx.x * NT + threadIdx.x;   // over B*64
  int b = i >> 6, d = i & 63;
  out[i] = wtab[(size_t)y[b]*D_N + d];     // FLOAT32 output
}

extern "C" void kernel_launch(void* const* d_in, const int* in_sizes, int n_in,
                              void* d_out, int out_size, void* d_ws, size_t ws_size,
                              hipStream_t stream) {
  (void)in_sizes; (void)n_in; (void)out_size;
  const int*   x    = (const int*)d_in[0];
  const int*   y    = (const int*)d_in[1];
  const float* cemb = (const float*)d_in[2];
  const float* wemb = (const float*)d_in[3];
  const float* W1   = (const float*)d_in[4];
  const float* b1   = (const float*)d_in[5];
  const float* W2   = (const float*)d_in[6];
  const float* b2   = (const float*)d_in[7];
  const float* Wr1  = (const float*)d_in[8];
  const float* br1  = (const float*)d_in[9];
  const float* Wr2  = (const float*)d_in[10];
  // br2 (d_in[11]): constant shift of all rewards -> argmin-invariant; unused.

  // ws layout: rew f64[B][32] @0 (8 MiB); sel i32[B] @8MiB;
  //            W1t f64 @9MiB (16 MiB); W2t f64 @25MiB (2 MiB);
  //            Wct f64 @29MiB (128 KiB); Wpt @29MiB+128KiB (64 KiB);
  //            hctx f64[B][128] @30MiB (32 MiB) -> needs 62 MiB total
  double* ws_rew = (double*)d_ws;
  int*    ws_sel = (int*)((char*)d_ws + (8ull<<20));
  double* W1t    = (double*)((char*)d_ws + (9ull<<20));
  double* W2t    = (double*)((char*)d_ws + (25ull<<20));
  double* Wct    = (double*)((char*)d_ws + (29ull<<20));
  double* Wpt    = (double*)((char*)d_ws + (29ull<<20) + (128ull<<10));
  double* hctxW  = (double*)((char*)d_ws + (30ull<<20));
  const bool tr1 = ws_size >= (30ull<<20);
  const bool tr2 = ws_size >= (62ull<<20);

  float* out_r    = (float*)d_out;                    // [B][64] f32
  float* out_wemb = out_r + (size_t)B_TOT * D_N;      // [B][64] f32

  if (tr2) {
    kT<<<dim3(32, 10), dim3(NT), 0, stream>>>(W1, W2, Wr1, W1t, W2t, Wct, Wpt);
    k1_hctx<<<dim3(B_TOT/BT), dim3(NT), 0, stream>>>(x, cemb, Wct, hctxW);
    k2_rewards<true,true><<<dim3(B_TOT/BT, A_N), dim3(NT), 0, stream>>>(
        x, cemb, W1, b1, W2, b2, Wr1, br1, Wr2, W1t, W2t, Wct, Wpt, hctxW, ws_rew);
  } else if (tr1) {
    kT<<<dim3(32, 10), dim3(NT), 0, stream>>>(W1, W2, Wr1, W1t, W2t, Wct, Wpt);
    k2_rewards<true,false><<<dim3(B_TOT/BT, A_N), dim3(NT), 0, stream>>>(
        x, cemb, W1, b1, W2, b2, Wr1, br1, Wr2, W1t, W2t, Wct, Wpt, nullptr, ws_rew);
  } else {
    k2_rewards<false,false><<<dim3(B_TOT/BT, A_N), dim3(NT), 0, stream>>>(
        x, cemb, W1, b1, W2, b2, Wr1, br1, Wr2, nullptr, nullptr, nullptr, nullptr,
        nullptr, ws_rew);
  }
  k3_argmin<<<dim3(B_TOT/NT), dim3(NT), 0, stream>>>(ws_rew, ws_sel);
  if (tr1) {
    k4_out<true><<<dim3(B_TOT/BT), dim3(NT), 0, stream>>>(
        x, cemb, W1, b1, W2, b2, W1t, W2t, ws_sel, out_r);
  } else {
    k4_out<false><<<dim3(B_TOT/BT), dim3(NT), 0, stream>>>(
        x, cemb, W1, b1, W2, b2, nullptr, nullptr, ws_sel, out_r);
  }
  k5_wemb<<<dim3(B_TOT*D_N/NT), dim3(NT), 0, stream>>>(y, wemb, out_wemb);
}